// Round 2
// baseline (128.738 us; speedup 1.0000x reference)
//
#include <hip/hip_runtime.h>
#include <hip/hip_bf16.h>
#include <math.h>

// GAT forward, N=4096, FIN=128, H=4, FOUT=64.  All inputs f32, output f32.
//
// Round 12: k1 latency surgery.  Accounting across rounds says ~84 us of the
// 127 us is the harness's two 256-MiB poison fills; k0 ~8 us; k1 ~35 us with
// the mask phase still at ~2 TB/s.  Three coordinated changes to k1:
//   1. 2 rows/block, grid 2048 -> ALL blocks resident in one pass (8/CU);
//      row1's mask loads issue once row0's hitmask is built (its mask regs
//      are dead), hiding row1 HBM latency under row0's softmax/gather.
//   2. Scan: per-lane 16-bit hitmask + 6-step shfl_up prefix sum replaces
//      the 16-round ballot/mbcnt serial chain; hits are written DIRECTLY
//      into the merged s_j (no per-wave segment buffer, no copy pass).
//   3. Gather unrolled 4-deep (4 independent 8B loads in flight).
// k0_gemm unchanged.
//
// ws layout (bytes):
//   h2b     [N][H*FO] bf16   offset 0       (2 MB)
//   skip_ws [N][H*FO] f32    offset 2 MB    (4 MB)
//   src4    [N][4]    f32    offset 6 MB    (64 KB)
//   tgt4    [N][4]    f32    offset 6 MB+64K(64 KB)

#define NN   4096
#define FIN  128
#define NH   4
#define FO   64
#define HF   256
#define LIST 192         // per-row cap (mean ~83, never binds in practice)
#define GEMM_BLOCKS 512
#define ROWS_PER 2

typedef unsigned short ushort_t;
typedef unsigned int uint4n __attribute__((ext_vector_type(4)));

__device__ __forceinline__ ushort_t f2bf(float f) {
    __hip_bfloat16 h = __float2bfloat16(f);
    union { __hip_bfloat16 h; ushort_t u; } c; c.h = h; return c.u;
}
__device__ __forceinline__ float bf2f(ushort_t u) {
    union { unsigned int i; float f; } c; c.i = ((unsigned int)u) << 16; return c.f;
}

// ---------------------------------------------------------------------------
// k0_gemm: x @ [proj | skip_w^T] -> h2b/skip_ws (+ s_src/s_tgt epilogue).
// 512 blocks (2/CU), 64x64 tile, K=128.  Unchanged.
// ---------------------------------------------------------------------------
__global__ __launch_bounds__(256) void k0_gemm(
        const float* __restrict__ x,      // [N][FIN]
        const float* __restrict__ proj,   // [H][FIN][FO]
        const float* __restrict__ skw,    // [HF][FIN]
        const float* __restrict__ asrc,   // [H][FO]
        const float* __restrict__ atgt,   // [H][FO]
        ushort_t* __restrict__ h2b, float* __restrict__ skip_ws,
        float* __restrict__ src4, float* __restrict__ tgt4) {
    __shared__ float sA[64 * 68];
    __shared__ float sB[64 * 64];
    const int tid = threadIdx.x;
    const int blk = blockIdx.x;

    const int bc = blk >> 6;            // 0..7
    const int i0 = (blk & 63) * 64;
    const int tx = tid & 15, ty = tid >> 4;
    const int r0 = ty << 2, c0 = tx << 2;
    float acc[4][4] = {};

    #pragma unroll
    for (int kb = 0; kb < FIN; kb += 64) {
        if (kb) __syncthreads();
        #pragma unroll
        for (int q = 0; q < 4; q++) {
            int s   = tid + q * 256;
            int row = s >> 4;
            int c4  = (s & 15) << 2;
            float4 v = *(const float4*)(x + (size_t)(i0 + row) * FIN + kb + c4);
            float* d = sA + row * 68 + c4;
            d[0] = v.x; d[1] = v.y; d[2] = v.z; d[3] = v.w;
        }
        if (bc < 4) {
            const float4* src = (const float4*)(proj + (size_t)bc * FIN * FO
                                                + (size_t)kb * FO);
            #pragma unroll
            for (int q = 0; q < 4; q++) {
                int s = tid + q * 256;
                *(float4*)(sB + (size_t)s * 4) = src[s];
            }
        } else {
            const float* sw = skw + (size_t)(bc - 4) * 64 * FIN;
            #pragma unroll
            for (int q = 0; q < 4; q++) {
                int s  = tid + q * 256;
                int c  = s & 63;
                int k4 = (s >> 6) << 2;
                float4 v = *(const float4*)(sw + (size_t)c * FIN + kb + k4);
                sB[(k4 + 0) * 64 + c] = v.x;
                sB[(k4 + 1) * 64 + c] = v.y;
                sB[(k4 + 2) * 64 + c] = v.z;
                sB[(k4 + 3) * 64 + c] = v.w;
            }
        }
        __syncthreads();

        #pragma unroll 2
        for (int k = 0; k < 64; k += 4) {
            alignas(16) float a[4][4];
            alignas(16) float b[4][4];
            #pragma unroll
            for (int rr = 0; rr < 4; rr++)
                *(float4*)a[rr] = *(const float4*)(sA + (r0 + rr) * 68 + k);
            #pragma unroll
            for (int kk = 0; kk < 4; kk++)
                *(float4*)b[kk] = *(const float4*)(sB + (k + kk) * 64 + c0);
            #pragma unroll
            for (int kk = 0; kk < 4; kk++)
                #pragma unroll
                for (int rr = 0; rr < 4; rr++)
                    #pragma unroll
                    for (int cc = 0; cc < 4; cc++)
                        acc[rr][cc] = fmaf(a[rr][kk], b[kk][cc], acc[rr][cc]);
        }
    }

    if (bc < 4) {
        #pragma unroll
        for (int rr = 0; rr < 4; rr++) {
            ushort4 hv;
            hv.x = f2bf(acc[rr][0]); hv.y = f2bf(acc[rr][1]);
            hv.z = f2bf(acc[rr][2]); hv.w = f2bf(acc[rr][3]);
            *(ushort4*)(h2b + (size_t)(i0 + r0 + rr) * HF + bc * 64 + c0) = hv;
        }
        float as[4], at[4];
        #pragma unroll
        for (int cc = 0; cc < 4; cc++) {
            as[cc] = asrc[bc * FO + c0 + cc];
            at[cc] = atgt[bc * FO + c0 + cc];
        }
        #pragma unroll
        for (int rr = 0; rr < 4; rr++) {
            float ps = acc[rr][0] * as[0] + acc[rr][1] * as[1]
                     + acc[rr][2] * as[2] + acc[rr][3] * as[3];
            float pt = acc[rr][0] * at[0] + acc[rr][1] * at[1]
                     + acc[rr][2] * at[2] + acc[rr][3] * at[3];
            #pragma unroll
            for (int off = 8; off >= 1; off >>= 1) {
                ps += __shfl_xor(ps, off, 64);
                pt += __shfl_xor(pt, off, 64);
            }
            if (tx == 0) {
                int i = i0 + r0 + rr;
                src4[(size_t)i * 4 + bc] = ps;
                tgt4[(size_t)i * 4 + bc] = pt;
            }
        }
    } else {
        float* dst = skip_ws + (size_t)i0 * HF + (bc - 4) * 64;
        #pragma unroll
        for (int rr = 0; rr < 4; rr++)
            *(float4*)(dst + (size_t)(r0 + rr) * HF + c0) = *(float4*)acc[rr];
    }
}

// ---------------------------------------------------------------------------
// k1_attn: fused scan + softmax + aggregate + epilogue.  2 rows per block.
// ---------------------------------------------------------------------------
struct K1Shared {
    int   s_j[LIST];
    float s_p[4][LIST + 1];
    float s_red[4][256];
    int   s_cnt[4];
    float s_inv[4];
};

__device__ __forceinline__ void k1_row(
        K1Shared* sh, unsigned hm, float sc, float skipv, float bv, int i,
        int tid, int lane, int w,
        const ushort_t* __restrict__ h2b,
        const float* __restrict__ tgt4,
        float* __restrict__ out) {
    // ---- prefix-sum compaction: write hits directly into merged s_j ----
    const int cl = __popc(hm);
    int incl = cl;
    #pragma unroll
    for (int o = 1; o < 64; o <<= 1) {
        int t = __shfl_up(incl, o, 64);
        if (lane >= o) incl += t;
    }
    const int excl = incl - cl;
    if (lane == 63) sh->s_cnt[w] = incl;     // wave total
    __syncthreads();
    const int t0 = sh->s_cnt[0], t1 = sh->s_cnt[1],
              t2 = sh->s_cnt[2], t3 = sh->s_cnt[3];
    const int off = (w > 0 ? t0 : 0) + (w > 1 ? t1 : 0) + (w > 2 ? t2 : 0);
    int c = t0 + t1 + t2 + t3;
    c = c < LIST ? c : LIST;

    int p = off + excl;
    unsigned mm = hm;
    while (mm) {
        int b = __builtin_ctz(mm);
        mm &= mm - 1;
        if (p < LIST)
            sh->s_j[p] = (w << 10) + ((b >> 2) << 8) + (lane << 2) + (b & 3);
        p++;
    }
    __syncthreads();

    // ---- softmax numerators: wave w owns head w ----
    float lsum = 0.f;
    for (int kk = lane; kk < c; kk += 64) {
        int j = sh->s_j[kk];
        float pv = sc + tgt4[(size_t)j * 4 + w];
        pv = pv > 0.f ? pv : 0.2f * pv;
        pv = __expf(pv);
        sh->s_p[w][kk] = pv;
        lsum += pv;
    }
    #pragma unroll
    for (int o = 32; o >= 1; o >>= 1)
        lsum += __shfl_xor(lsum, o, 64);
    if (lane == 0) sh->s_inv[w] = lsum > 0.f ? 1.0f / lsum : 0.0f;
    __syncthreads();

    // ---- widened gather: each wave covers all 256 cols (8B/lane),
    //      waves split the j-list 4 ways, 4-deep unroll ----
    const int h = lane >> 4;
    const ushort_t* hp = h2b + 4 * lane;
    float4 acc = {0.f, 0.f, 0.f, 0.f};
    int kk = w;
    for (; kk + 12 < c; kk += 16) {
        int   j0 = sh->s_j[kk],      j1 = sh->s_j[kk + 4];
        int   j2 = sh->s_j[kk + 8],  j3 = sh->s_j[kk + 12];
        float p0 = sh->s_p[h][kk],   p1 = sh->s_p[h][kk + 4];
        float p2 = sh->s_p[h][kk + 8], p3 = sh->s_p[h][kk + 12];
        ushort4 a0 = *(const ushort4*)(hp + (size_t)j0 * HF);
        ushort4 a1 = *(const ushort4*)(hp + (size_t)j1 * HF);
        ushort4 a2 = *(const ushort4*)(hp + (size_t)j2 * HF);
        ushort4 a3 = *(const ushort4*)(hp + (size_t)j3 * HF);
        acc.x = fmaf(p0, bf2f(a0.x), acc.x);
        acc.y = fmaf(p0, bf2f(a0.y), acc.y);
        acc.z = fmaf(p0, bf2f(a0.z), acc.z);
        acc.w = fmaf(p0, bf2f(a0.w), acc.w);
        acc.x = fmaf(p1, bf2f(a1.x), acc.x);
        acc.y = fmaf(p1, bf2f(a1.y), acc.y);
        acc.z = fmaf(p1, bf2f(a1.z), acc.z);
        acc.w = fmaf(p1, bf2f(a1.w), acc.w);
        acc.x = fmaf(p2, bf2f(a2.x), acc.x);
        acc.y = fmaf(p2, bf2f(a2.y), acc.y);
        acc.z = fmaf(p2, bf2f(a2.z), acc.z);
        acc.w = fmaf(p2, bf2f(a2.w), acc.w);
        acc.x = fmaf(p3, bf2f(a3.x), acc.x);
        acc.y = fmaf(p3, bf2f(a3.y), acc.y);
        acc.z = fmaf(p3, bf2f(a3.z), acc.z);
        acc.w = fmaf(p3, bf2f(a3.w), acc.w);
    }
    for (; kk < c; kk += 4) {
        int   j0 = sh->s_j[kk];
        float p0 = sh->s_p[h][kk];
        ushort4 a0 = *(const ushort4*)(hp + (size_t)j0 * HF);
        acc.x = fmaf(p0, bf2f(a0.x), acc.x);
        acc.y = fmaf(p0, bf2f(a0.y), acc.y);
        acc.z = fmaf(p0, bf2f(a0.z), acc.z);
        acc.w = fmaf(p0, bf2f(a0.w), acc.w);
    }
    *(float4*)&sh->s_red[w][4 * lane] = acc;
    __syncthreads();

    // ---- epilogue: col = tid ----
    float tot = sh->s_red[0][tid] + sh->s_red[1][tid]
              + sh->s_red[2][tid] + sh->s_red[3][tid];
    float vv = tot * sh->s_inv[tid >> 6] + skipv + bv;
    vv = vv > 0.f ? vv : expm1f(vv);
    out[(size_t)i * HF + tid] = vv;
}

__global__ __launch_bounds__(256) void k1_attn(
        const unsigned int* __restrict__ mask,   // f32 bits [N][N]
        const ushort_t* __restrict__ h2b,        // [N][HF] bf16
        const float* __restrict__ skip_ws,       // [N][HF]
        const float* __restrict__ src4,          // [N][4]
        const float* __restrict__ tgt4,          // [N][4]
        const float* __restrict__ bias,          // [HF]
        float* __restrict__ out) {               // [N][HF]
    __shared__ K1Shared sh;
    const int tid  = threadIdx.x;
    const int lane = tid & 63, w = tid >> 6;
    const int i0   = blockIdx.x * ROWS_PER;

    // ---- row0 mask loads first ----
    const uint4n* mb = (const uint4n*)mask;
    const size_t base = (size_t)i0 * 1024 + (size_t)(w * 256 + lane);
    uint4n m0[4];
    #pragma unroll
    for (int s = 0; s < 4; s++) m0[s] = mb[base + s * 64];

    // independent epilogue loads (col = tid)
    const float skip0 = skip_ws[(size_t)i0 * HF + tid];
    const float skip1 = skip_ws[(size_t)(i0 + 1) * HF + tid];
    const float bv    = bias[tid];
    const float sc0   = src4[(size_t)i0 * 4 + w];
    const float sc1   = src4[(size_t)(i0 + 1) * 4 + w];

    // ---- row0 hitmask (m0 regs die here) ----
    unsigned hm0 = 0;
    #pragma unroll
    for (int s = 0; s < 4; s++)
        #pragma unroll
        for (int e = 0; e < 4; e++)
            hm0 |= ((m0[s][e] & 0x7fffffffu) == 0u ? 1u : 0u) << (s * 4 + e);

    // ---- issue row1 mask loads; latency hides under ALL of row0's work ----
    uint4n m1[4];
    #pragma unroll
    for (int s = 0; s < 4; s++) m1[s] = mb[base + 1024 + s * 64];

    k1_row(&sh, hm0, sc0, skip0, bv, i0, tid, lane, w, h2b, tgt4, out);
    __syncthreads();   // WAR: row1 reuses s_j/s_p/s_red

    unsigned hm1 = 0;
    #pragma unroll
    for (int s = 0; s < 4; s++)
        #pragma unroll
        for (int e = 0; e < 4; e++)
            hm1 |= ((m1[s][e] & 0x7fffffffu) == 0u ? 1u : 0u) << (s * 4 + e);

    k1_row(&sh, hm1, sc1, skip1, bv, i0 + 1, tid, lane, w, h2b, tgt4, out);
}

extern "C" void kernel_launch(void* const* d_in, const int* in_sizes, int n_in,
                              void* d_out, int out_size, void* d_ws, size_t ws_size,
                              hipStream_t stream) {
    const float*        x    = (const float*)d_in[0];
    const unsigned int* mask = (const unsigned int*)d_in[1];
    const float*        proj = (const float*)d_in[2];
    const float*        asrc = (const float*)d_in[3];
    const float*        atgt = (const float*)d_in[4];
    const float*        skw  = (const float*)d_in[5];
    const float*        bias = (const float*)d_in[6];
    float*              out  = (float*)d_out;

    char* ws = (char*)d_ws;
    ushort_t* h2b     = (ushort_t*)ws;                          // 2 MB
    float*    skip_ws = (float*)(ws + (2u << 20));              // 4 MB
    float*    src4    = (float*)(ws + (6u << 20));              // 64 KB
    float*    tgt4    = (float*)(ws + (6u << 20) + (64u << 10));// 64 KB

    hipLaunchKernelGGL(k0_gemm, dim3(GEMM_BLOCKS), dim3(256), 0, stream,
                       x, proj, skw, asrc, atgt,
                       h2b, skip_ws, src4, tgt4);
    hipLaunchKernelGGL(k1_attn, dim3(NN / ROWS_PER), dim3(256), 0, stream,
                       mask, h2b, skip_ws, src4, tgt4, bias, out);
}

// Round 3
// 127.672 us; speedup vs baseline: 1.0084x; 1.0084x over previous
//
#include <hip/hip_runtime.h>
#include <hip/hip_bf16.h>
#include <math.h>

// GAT forward, N=4096, FIN=128, H=4, FOUT=64.  All inputs f32, output f32.
//
// Round 13: barrier-free k1.  Rounds 11/12 falsified the scan-chain and
// dispatch-shape theories: k1 is stuck at ~33 us (mask ~1.9 TB/s) across
// three different structures.  The invariant is the coupled 4-wave block
// with 4-8 __syncthreads per row: every few hundred cycles all waves of a
// block park at the same vmcnt-drain + barrier, so the CU scheduler
// repeatedly runs out of runnable waves.  This round: ONE WAVE PER ROW,
// zero barriers.  Each wave: 16 KB mask row (16 coalesced dwordx4, all in
// flight) -> 64-bit hitmask -> shfl_up prefix compaction into PRIVATE LDS
// segment -> per-head softmax in 16-lane subgroups (shfl_xor <=8) ->
// packed {p, byteoff} b64 records -> widened 256-col gather (8B/lane).
// All LDS is intra-wave (waitcnt-ordered, no barrier); the s_red
// cross-wave reduction disappears (wave owns the whole output row).
// 4096 independent waves = maximal scheduler freedom.
// k0_gemm unchanged.
//
// ws layout (bytes):
//   h2b     [N][H*FO] bf16   offset 0       (2 MB)
//   skip_ws [N][H*FO] f32    offset 2 MB    (4 MB)
//   src4    [N][4]    f32    offset 6 MB    (64 KB)
//   tgt4    [N][4]    f32    offset 6 MB+64K(64 KB)

#define NN   4096
#define FIN  128
#define NH   4
#define FO   64
#define HF   256
#define LIST 192         // per-row cap (mean ~83, max ~115; never binds)
#define GEMM_BLOCKS 512

typedef unsigned short ushort_t;
typedef unsigned int uint4n __attribute__((ext_vector_type(4)));

__device__ __forceinline__ ushort_t f2bf(float f) {
    __hip_bfloat16 h = __float2bfloat16(f);
    union { __hip_bfloat16 h; ushort_t u; } c; c.h = h; return c.u;
}
__device__ __forceinline__ float bf2f(ushort_t u) {
    union { unsigned int i; float f; } c; c.i = ((unsigned int)u) << 16; return c.f;
}

// ---------------------------------------------------------------------------
// k0_gemm: x @ [proj | skip_w^T] -> h2b/skip_ws (+ s_src/s_tgt epilogue).
// 512 blocks (2/CU), 64x64 tile, K=128.  Unchanged.
// ---------------------------------------------------------------------------
__global__ __launch_bounds__(256) void k0_gemm(
        const float* __restrict__ x,      // [N][FIN]
        const float* __restrict__ proj,   // [H][FIN][FO]
        const float* __restrict__ skw,    // [HF][FIN]
        const float* __restrict__ asrc,   // [H][FO]
        const float* __restrict__ atgt,   // [H][FO]
        ushort_t* __restrict__ h2b, float* __restrict__ skip_ws,
        float* __restrict__ src4, float* __restrict__ tgt4) {
    __shared__ float sA[64 * 68];
    __shared__ float sB[64 * 64];
    const int tid = threadIdx.x;
    const int blk = blockIdx.x;

    const int bc = blk >> 6;            // 0..7
    const int i0 = (blk & 63) * 64;
    const int tx = tid & 15, ty = tid >> 4;
    const int r0 = ty << 2, c0 = tx << 2;
    float acc[4][4] = {};

    #pragma unroll
    for (int kb = 0; kb < FIN; kb += 64) {
        if (kb) __syncthreads();
        #pragma unroll
        for (int q = 0; q < 4; q++) {
            int s   = tid + q * 256;
            int row = s >> 4;
            int c4  = (s & 15) << 2;
            float4 v = *(const float4*)(x + (size_t)(i0 + row) * FIN + kb + c4);
            float* d = sA + row * 68 + c4;
            d[0] = v.x; d[1] = v.y; d[2] = v.z; d[3] = v.w;
        }
        if (bc < 4) {
            const float4* src = (const float4*)(proj + (size_t)bc * FIN * FO
                                                + (size_t)kb * FO);
            #pragma unroll
            for (int q = 0; q < 4; q++) {
                int s = tid + q * 256;
                *(float4*)(sB + (size_t)s * 4) = src[s];
            }
        } else {
            const float* sw = skw + (size_t)(bc - 4) * 64 * FIN;
            #pragma unroll
            for (int q = 0; q < 4; q++) {
                int s  = tid + q * 256;
                int c  = s & 63;
                int k4 = (s >> 6) << 2;
                float4 v = *(const float4*)(sw + (size_t)c * FIN + kb + k4);
                sB[(k4 + 0) * 64 + c] = v.x;
                sB[(k4 + 1) * 64 + c] = v.y;
                sB[(k4 + 2) * 64 + c] = v.z;
                sB[(k4 + 3) * 64 + c] = v.w;
            }
        }
        __syncthreads();

        #pragma unroll 2
        for (int k = 0; k < 64; k += 4) {
            alignas(16) float a[4][4];
            alignas(16) float b[4][4];
            #pragma unroll
            for (int rr = 0; rr < 4; rr++)
                *(float4*)a[rr] = *(const float4*)(sA + (r0 + rr) * 68 + k);
            #pragma unroll
            for (int kk = 0; kk < 4; kk++)
                *(float4*)b[kk] = *(const float4*)(sB + (k + kk) * 64 + c0);
            #pragma unroll
            for (int kk = 0; kk < 4; kk++)
                #pragma unroll
                for (int rr = 0; rr < 4; rr++)
                    #pragma unroll
                    for (int cc = 0; cc < 4; cc++)
                        acc[rr][cc] = fmaf(a[rr][kk], b[kk][cc], acc[rr][cc]);
        }
    }

    if (bc < 4) {
        #pragma unroll
        for (int rr = 0; rr < 4; rr++) {
            ushort4 hv;
            hv.x = f2bf(acc[rr][0]); hv.y = f2bf(acc[rr][1]);
            hv.z = f2bf(acc[rr][2]); hv.w = f2bf(acc[rr][3]);
            *(ushort4*)(h2b + (size_t)(i0 + r0 + rr) * HF + bc * 64 + c0) = hv;
        }
        float as[4], at[4];
        #pragma unroll
        for (int cc = 0; cc < 4; cc++) {
            as[cc] = asrc[bc * FO + c0 + cc];
            at[cc] = atgt[bc * FO + c0 + cc];
        }
        #pragma unroll
        for (int rr = 0; rr < 4; rr++) {
            float ps = acc[rr][0] * as[0] + acc[rr][1] * as[1]
                     + acc[rr][2] * as[2] + acc[rr][3] * as[3];
            float pt = acc[rr][0] * at[0] + acc[rr][1] * at[1]
                     + acc[rr][2] * at[2] + acc[rr][3] * at[3];
            #pragma unroll
            for (int off = 8; off >= 1; off >>= 1) {
                ps += __shfl_xor(ps, off, 64);
                pt += __shfl_xor(pt, off, 64);
            }
            if (tx == 0) {
                int i = i0 + r0 + rr;
                src4[(size_t)i * 4 + bc] = ps;
                tgt4[(size_t)i * 4 + bc] = pt;
            }
        }
    } else {
        float* dst = skip_ws + (size_t)i0 * HF + (bc - 4) * 64;
        #pragma unroll
        for (int rr = 0; rr < 4; rr++)
            *(float4*)(dst + (size_t)(r0 + rr) * HF + c0) = *(float4*)acc[rr];
    }
}

// ---------------------------------------------------------------------------
// k1_attn: one WAVE per row, zero barriers.  1024 blocks x 256 threads.
// ---------------------------------------------------------------------------
__global__ __launch_bounds__(256, 4) void k1_attn(
        const unsigned int* __restrict__ mask,   // f32 bits [N][N]
        const ushort_t* __restrict__ h2b,        // [N][HF] bf16
        const float* __restrict__ skip_ws,       // [N][HF]
        const float* __restrict__ src4,          // [N][4]
        const float* __restrict__ tgt4,          // [N][4]
        const float* __restrict__ bias,          // [HF]
        float* __restrict__ out) {               // [N][HF]
    // per-wave private LDS (intra-wave only; no barriers anywhere)
    __shared__ ushort_t s_j[4][LIST];            // col indices
    __shared__ uint2    s_rec[4][4][LIST + 1];   // [wave][head][kk] {p bits, byteoff}
    const int tid  = threadIdx.x;
    const int lane = tid & 63, w = tid >> 6;
    const int i    = blockIdx.x * 4 + w;         // this wave's row
    const int h    = lane >> 4;                  // head owned by this lane's subgroup
    const int g    = lane & 15;                  // lane within subgroup

    // ---- mask row: 16 coalesced dwordx4, all in flight (16 KB/wave) ----
    const uint4n* mb = (const uint4n*)(mask + (size_t)i * NN);
    uint4n m[16];
    #pragma unroll
    for (int s = 0; s < 16; s++) m[s] = mb[s * 64 + lane];

    // independent operand loads (hide under mask latency)
    const float4 skipv = *(const float4*)(skip_ws + (size_t)i * HF + 4 * lane);
    const float4 bv    = *(const float4*)(bias + 4 * lane);
    const float  sc    = src4[(size_t)i * 4 + h];

    // ---- 64-bit hitmask: bit (s*4+e) <-> col s*256 + lane*4 + e ----
    unsigned long long hm = 0ull;
    #pragma unroll
    for (int s = 0; s < 16; s++)
        #pragma unroll
        for (int e = 0; e < 4; e++)
            if ((m[s][e] & 0x7fffffffu) == 0u)
                hm |= 1ull << (s * 4 + e);

    // ---- wave prefix sum over per-lane hit counts ----
    const int cl = __popcll(hm);
    int incl = cl;
    #pragma unroll
    for (int o = 1; o < 64; o <<= 1) {
        int t = __shfl_up(incl, o, 64);
        if (lane >= o) incl += t;
    }
    const int excl = incl - cl;
    int c = __shfl(incl, 63, 64);
    c = c < LIST ? c : LIST;

    // ---- compact col indices into this wave's private segment ----
    {
        int p = excl;
        unsigned long long mm = hm;
        while (mm) {
            int b = __builtin_ctzll(mm);
            mm &= mm - 1;
            if (p < LIST)
                s_j[w][p] = (ushort_t)((b >> 2) * 256 + lane * 4 + (b & 3));
            p++;
        }
    }
    // intra-wave LDS RAW: ordered by lgkmcnt waits, no barrier needed.

    // ---- softmax: 16-lane subgroup g owns head h for this row ----
    float lsum = 0.f;
    for (int kk = g; kk < c; kk += 16) {
        int j = s_j[w][kk];
        float pv = sc + tgt4[(size_t)j * 4 + h];
        pv = pv > 0.f ? pv : 0.2f * pv;
        pv = __expf(pv);
        uint2 r;
        r.x = __float_as_uint(pv);
        r.y = (unsigned)j << 9;                  // byte offset into h2b row
        s_rec[w][h][kk] = r;
        lsum += pv;
    }
    #pragma unroll
    for (int o = 8; o >= 1; o >>= 1)
        lsum += __shfl_xor(lsum, o, 64);         // stays within 16-lane group
    const float inv = lsum > 0.f ? 1.0f / lsum : 0.0f;

    // ---- widened gather: this wave covers all 256 cols (8B/lane) ----
    const char* hp = (const char*)(h2b + 4 * lane);
    float4 acc = {0.f, 0.f, 0.f, 0.f};
    int kk = 0;
    for (; kk + 3 < c; kk += 4) {
        uint2 r0 = s_rec[w][h][kk + 0];
        uint2 r1 = s_rec[w][h][kk + 1];
        uint2 r2 = s_rec[w][h][kk + 2];
        uint2 r3 = s_rec[w][h][kk + 3];
        ushort4 a0 = *(const ushort4*)(hp + r0.y);
        ushort4 a1 = *(const ushort4*)(hp + r1.y);
        ushort4 a2 = *(const ushort4*)(hp + r2.y);
        ushort4 a3 = *(const ushort4*)(hp + r3.y);
        float p0 = __uint_as_float(r0.x), p1 = __uint_as_float(r1.x);
        float p2 = __uint_as_float(r2.x), p3 = __uint_as_float(r3.x);
        acc.x = fmaf(p0, bf2f(a0.x), acc.x);
        acc.y = fmaf(p0, bf2f(a0.y), acc.y);
        acc.z = fmaf(p0, bf2f(a0.z), acc.z);
        acc.w = fmaf(p0, bf2f(a0.w), acc.w);
        acc.x = fmaf(p1, bf2f(a1.x), acc.x);
        acc.y = fmaf(p1, bf2f(a1.y), acc.y);
        acc.z = fmaf(p1, bf2f(a1.z), acc.z);
        acc.w = fmaf(p1, bf2f(a1.w), acc.w);
        acc.x = fmaf(p2, bf2f(a2.x), acc.x);
        acc.y = fmaf(p2, bf2f(a2.y), acc.y);
        acc.z = fmaf(p2, bf2f(a2.z), acc.z);
        acc.w = fmaf(p2, bf2f(a2.w), acc.w);
        acc.x = fmaf(p3, bf2f(a3.x), acc.x);
        acc.y = fmaf(p3, bf2f(a3.y), acc.y);
        acc.z = fmaf(p3, bf2f(a3.z), acc.z);
        acc.w = fmaf(p3, bf2f(a3.w), acc.w);
    }
    for (; kk < c; kk++) {
        uint2 r0 = s_rec[w][h][kk];
        ushort4 a0 = *(const ushort4*)(hp + r0.y);
        float p0 = __uint_as_float(r0.x);
        acc.x = fmaf(p0, bf2f(a0.x), acc.x);
        acc.y = fmaf(p0, bf2f(a0.y), acc.y);
        acc.z = fmaf(p0, bf2f(a0.z), acc.z);
        acc.w = fmaf(p0, bf2f(a0.w), acc.w);
    }

    // ---- epilogue: this lane owns cols 4*lane .. 4*lane+3 of row i ----
    float4 vv;
    vv.x = acc.x * inv + skipv.x + bv.x;
    vv.y = acc.y * inv + skipv.y + bv.y;
    vv.z = acc.z * inv + skipv.z + bv.z;
    vv.w = acc.w * inv + skipv.w + bv.w;
    vv.x = vv.x > 0.f ? vv.x : expm1f(vv.x);
    vv.y = vv.y > 0.f ? vv.y : expm1f(vv.y);
    vv.z = vv.z > 0.f ? vv.z : expm1f(vv.z);
    vv.w = vv.w > 0.f ? vv.w : expm1f(vv.w);
    *(float4*)(out + (size_t)i * HF + 4 * lane) = vv;
}

extern "C" void kernel_launch(void* const* d_in, const int* in_sizes, int n_in,
                              void* d_out, int out_size, void* d_ws, size_t ws_size,
                              hipStream_t stream) {
    const float*        x    = (const float*)d_in[0];
    const unsigned int* mask = (const unsigned int*)d_in[1];
    const float*        proj = (const float*)d_in[2];
    const float*        asrc = (const float*)d_in[3];
    const float*        atgt = (const float*)d_in[4];
    const float*        skw  = (const float*)d_in[5];
    const float*        bias = (const float*)d_in[6];
    float*              out  = (float*)d_out;

    char* ws = (char*)d_ws;
    ushort_t* h2b     = (ushort_t*)ws;                          // 2 MB
    float*    skip_ws = (float*)(ws + (2u << 20));              // 4 MB
    float*    src4    = (float*)(ws + (6u << 20));              // 64 KB
    float*    tgt4    = (float*)(ws + (6u << 20) + (64u << 10));// 64 KB

    hipLaunchKernelGGL(k0_gemm, dim3(GEMM_BLOCKS), dim3(256), 0, stream,
                       x, proj, skw, asrc, atgt,
                       h2b, skip_ws, src4, tgt4);
    hipLaunchKernelGGL(k1_attn, dim3(NN / 4), dim3(256), 0, stream,
                       mask, h2b, skip_ws, src4, tgt4, bias, out);
}